// Round 2
// baseline (352.490 us; speedup 1.0000x reference)
//
#include <hip/hip_runtime.h>

#define NN 5000
#define NE 40000

__device__ __forceinline__ float siluf(float x) { return x / (1.f + __expf(-x)); }

__device__ __forceinline__ float dot8(const float* h, float4 a, float4 b) {
  return h[0]*a.x + h[1]*a.y + h[2]*a.z + h[3]*a.w
       + h[4]*b.x + h[5]*b.y + h[6]*b.z + h[7]*b.w;
}

__device__ __forceinline__ void mlp8(const float* ea, const float* __restrict__ W0,
                                     const float* __restrict__ b0, float* h) {
#pragma unroll
  for (int j = 0; j < 8; j++) {
    float a = b0[j];
#pragma unroll
    for (int i = 0; i < 8; i++) a += ea[i] * W0[i*8 + j];
    h[j] = siluf(a);
  }
}

// ---- geometry + all three radial-MLP hidden activations + in-degree counts ----
__global__ void k_geom(const float* __restrict__ coords, const int* __restrict__ eidx,
                       const float* __restrict__ ipW0, const float* __restrict__ ipb0,
                       const float* __restrict__ lyW0, const float* __restrict__ lyb0,
                       const float* __restrict__ etW0, const float* __restrict__ etb0,
                       float* __restrict__ sh, float* __restrict__ h_ip,
                       float* __restrict__ h_ly, float* __restrict__ h_et,
                       float* __restrict__ cnt) {
  int e = blockIdx.x * blockDim.x + threadIdx.x;
  if (e >= NE) return;
  int s = eidx[e], d = eidx[NE + e];
  float vx = coords[d*3+0] - coords[s*3+0];
  float vy = coords[d*3+1] - coords[s*3+1];
  float vz = coords[d*3+2] - coords[s*3+2];
  float dist = sqrtf(vx*vx + vy*vy + vz*vz + 1e-12f);
  float inv = 1.f / dist;
  const float SQ3 = 1.7320508075688772f;
  sh[e*3+0] = SQ3 * vy * inv;   // e3nn (y,z,x) order
  sh[e*3+1] = SQ3 * vz * inv;
  sh[e*3+2] = SQ3 * vx * inv;
  float ea[8];
  const float step = 5.f / 9.f;
#pragma unroll
  for (int j = 0; j < 8; j++) {
    float diff = (dist - step * (float)(j+1)) * (9.f / 5.f);
    ea[j] = __expf(-diff*diff) * (1.f / 1.12f);
  }
  float h[8];
  mlp8(ea, ipW0, ipb0, h);
#pragma unroll
  for (int j = 0; j < 8; j++) h_ip[e*8+j] = h[j];
  mlp8(ea, lyW0, lyb0, h);
#pragma unroll
  for (int j = 0; j < 8; j++) h_ly[e*8+j] = h[j];
  mlp8(ea, etW0, etb0, h);
#pragma unroll
  for (int j = 0; j < 8; j++) h_et[e*8+j] = h[j];
  atomicAdd(&cnt[d], 1.f);
}

// ---- embedding gather ----
__global__ void k_embed(const int* __restrict__ at, const float* __restrict__ emb,
                        float* __restrict__ s0) {
  int t = blockIdx.x * blockDim.x + threadIdx.x;
  if (t >= NN*32) return;
  s0[t] = emb[at[t >> 5]*32 + (t & 31)];
}

// ---- scalar-driven conv: out_s += c*Σ su*w[j], out_v += c*sh_i*Σ su*w[1024+j] ----
// Covers k_e1 (both paths of init TP) and k_e2 paths {0,1}.
// Weight rows staged as float4 pairs: WA[j]=k0..3, WB[j]=k4..7 (64 KB total).
__global__ __launch_bounds__(256) void k_sconv(
    const float* __restrict__ hE, const float* __restrict__ sh,
    const float* __restrict__ sIn, const int* __restrict__ eidx,
    const float* __restrict__ W1, const float* __restrict__ b1,
    int ldw, int col0, float cscale,
    float* __restrict__ accS, float* __restrict__ accV) {
  __shared__ float4 WA[2048];
  __shared__ float4 WB[2048];
  for (int t = threadIdx.x; t < 4096; t += 256) {
    int j = t >> 1, half = t & 1;
    const float* src = W1 + (half*4)*ldw + col0 + j;
    float4 v;
    v.x = src[0]; v.y = src[ldw]; v.z = src[2*ldw]; v.w = src[3*ldw];
    if (half == 0) WA[j] = v; else WB[j] = v;
  }
  __syncthreads();
  const int g = threadIdx.x >> 5, tw = threadIdx.x & 31;
  const float* bS = b1 + col0;
  const float* bV = b1 + col0 + 1024;
  for (int p = blockIdx.x*8 + g; 2*p < NE; p += gridDim.x*8) {
    int e0 = 2*p, e1 = 2*p + 1;
    float h0[8], h1[8];
#pragma unroll
    for (int k = 0; k < 8; k++) { h0[k] = hE[e0*8+k]; h1[k] = hE[e1*8+k]; }
    int da = eidx[NE+e0], db = eidx[NE+e1];
    float sr0 = sIn[eidx[e0]*32 + tw];
    float sr1 = sIn[eidx[e1]*32 + tw];
    float a0s = 0.f, a0v = 0.f, a1s = 0.f, a1v = 0.f;
#pragma unroll 4
    for (int u = 0; u < 32; u++) {
      float su0 = __shfl(sr0, u, 32), su1 = __shfl(sr1, u, 32);
      int j = u*32 + tw;
      float4 qa = WA[j], qb = WB[j], ra = WA[1024+j], rb = WB[1024+j];
      float bbs = bS[j], bbv = bV[j];
      a0s += su0 * (bbs + dot8(h0, qa, qb));
      a1s += su1 * (bbs + dot8(h1, qa, qb));
      a0v += su0 * (bbv + dot8(h0, ra, rb));
      a1v += su1 * (bbv + dot8(h1, ra, rb));
    }
    atomicAdd(&accS[da*32 + tw], cscale*a0s);
    float m0 = cscale*a0v;
    atomicAdd(&accV[da*96 + tw*3 + 0], m0*sh[e0*3+0]);
    atomicAdd(&accV[da*96 + tw*3 + 1], m0*sh[e0*3+1]);
    atomicAdd(&accV[da*96 + tw*3 + 2], m0*sh[e0*3+2]);
    atomicAdd(&accS[db*32 + tw], cscale*a1s);
    float m1 = cscale*a1v;
    atomicAdd(&accV[db*96 + tw*3 + 0], m1*sh[e1*3+0]);
    atomicAdd(&accV[db*96 + tw*3 + 1], m1*sh[e1*3+1]);
    atomicAdd(&accV[db*96 + tw*3 + 2], m1*sh[e1*3+2]);
  }
}

// ---- vector-driven conv (k_e2 paths {2,3}): out_v += c*Σ vu_i*w2[j], out_s += c*Σ du*w3[1024+j] ----
__global__ __launch_bounds__(256) void k_vconv(
    const float* __restrict__ hE, const float* __restrict__ sh,
    const float* __restrict__ vIn, const int* __restrict__ eidx,
    const float* __restrict__ W1, const float* __restrict__ b1,
    float* __restrict__ accS, float* __restrict__ accV) {
  __shared__ float4 WA[2048];
  __shared__ float4 WB[2048];
  for (int t = threadIdx.x; t < 4096; t += 256) {
    int j = t >> 1, half = t & 1;
    const float* src = W1 + (half*4)*4096 + 2048 + j;
    float4 v;
    v.x = src[0]; v.y = src[4096]; v.z = src[8192]; v.w = src[12288];
    if (half == 0) WA[j] = v; else WB[j] = v;
  }
  __syncthreads();
  const int g = threadIdx.x >> 5, tw = threadIdx.x & 31;
  const float c = 0.125f;                 // 1/sqrt(64)
  const float is3 = 0.5773502691896258f;  // 1/sqrt(3)
  for (int p = blockIdx.x*8 + g; 2*p < NE; p += gridDim.x*8) {
    int e0 = 2*p, e1 = 2*p + 1;
    float h0[8], h1[8];
#pragma unroll
    for (int k = 0; k < 8; k++) { h0[k] = hE[e0*8+k]; h1[k] = hE[e1*8+k]; }
    int da = eidx[NE+e0], db = eidx[NE+e1];
    int sa = eidx[e0], sb = eidx[e1];
    float sh00 = sh[e0*3+0], sh01 = sh[e0*3+1], sh02 = sh[e0*3+2];
    float sh10 = sh[e1*3+0], sh11 = sh[e1*3+1], sh12 = sh[e1*3+2];
    float va0 = vIn[sa*96 + tw*3 + 0], va1 = vIn[sa*96 + tw*3 + 1], va2 = vIn[sa*96 + tw*3 + 2];
    float vb0 = vIn[sb*96 + tw*3 + 0], vb1 = vIn[sb*96 + tw*3 + 1], vb2 = vIn[sb*96 + tw*3 + 2];
    float dra = (va0*sh00 + va1*sh01 + va2*sh02) * is3;
    float drb = (vb0*sh10 + vb1*sh11 + vb2*sh12) * is3;
    float tv00 = 0.f, tv01 = 0.f, tv02 = 0.f, t3a = 0.f;
    float tv10 = 0.f, tv11 = 0.f, tv12 = 0.f, t3b = 0.f;
#pragma unroll 4
    for (int u = 0; u < 32; u++) {
      int j = u*32 + tw;
      float4 qa = WA[j], qb = WB[j], ra = WA[1024+j], rb = WB[1024+j];
      float b2 = b1[2048 + j], b3 = b1[3072 + j];
      float w2a = b2 + dot8(h0, qa, qb);
      float w2b = b2 + dot8(h1, qa, qb);
      float w3a = b3 + dot8(h0, ra, rb);
      float w3b = b3 + dot8(h1, ra, rb);
      float u0 = __shfl(va0, u, 32), u1 = __shfl(va1, u, 32), u2 = __shfl(va2, u, 32);
      float w0 = __shfl(vb0, u, 32), w1 = __shfl(vb1, u, 32), w2 = __shfl(vb2, u, 32);
      float dua = __shfl(dra, u, 32), dub = __shfl(drb, u, 32);
      tv00 += u0*w2a; tv01 += u1*w2a; tv02 += u2*w2a; t3a += dua*w3a;
      tv10 += w0*w2b; tv11 += w1*w2b; tv12 += w2*w2b; t3b += dub*w3b;
    }
    atomicAdd(&accS[da*32 + tw], c*t3a);
    atomicAdd(&accV[da*96 + tw*3 + 0], c*tv00);
    atomicAdd(&accV[da*96 + tw*3 + 1], c*tv01);
    atomicAdd(&accV[da*96 + tw*3 + 2], c*tv02);
    atomicAdd(&accS[db*32 + tw], c*t3b);
    atomicAdd(&accV[db*96 + tw*3 + 0], c*tv10);
    atomicAdd(&accV[db*96 + tw*3 + 1], c*tv11);
    atomicAdd(&accV[db*96 + tw*3 + 2], c*tv12);
  }
}

// ---- scatter-mean ----
__global__ void k_n1(const float* __restrict__ cnt, const float* __restrict__ accS,
                     const float* __restrict__ accV, float* __restrict__ s1,
                     float* __restrict__ v1) {
  int t = blockIdx.x * blockDim.x + threadIdx.x;
  if (t >= NN*32) return;
  float r = 1.f / fmaxf(cnt[t >> 5], 1.f);
  s1[t] = accS[t] * r;
  v1[t*3+0] = accV[t*3+0] * r;
  v1[t*3+1] = accV[t*3+1] * r;
  v1[t*3+2] = accV[t*3+2] * r;
}

// ---- mean + linear self-interaction ----
__global__ void k_n2(const float* __restrict__ cnt, const float* __restrict__ accS,
                     const float* __restrict__ accV, const float* __restrict__ s1,
                     const float* __restrict__ v1, const float* __restrict__ Ws,
                     const float* __restrict__ Wv, float* __restrict__ s2,
                     float* __restrict__ v2) {
  int t = blockIdx.x * blockDim.x + threadIdx.x;
  if (t >= NN*32) return;
  int n = t >> 5, w = t & 31;
  float r = 1.f / fmaxf(cnt[n], 1.f);
  const float lc = 0.17677669529663687f;  // 1/sqrt(32)
  float ss = 0.f, sv0 = 0.f, sv1 = 0.f, sv2 = 0.f;
#pragma unroll 8
  for (int u = 0; u < 32; u++) {
    ss += s1[n*32 + u] * Ws[u*32 + w];
    float wv = Wv[u*32 + w];
    sv0 += v1[n*96 + u*3 + 0] * wv;
    sv1 += v1[n*96 + u*3 + 1] * wv;
    sv2 += v1[n*96 + u*3 + 2] * wv;
  }
  s2[t] = accS[t]*r + lc*ss;
  v2[t*3+0] = accV[t*3+0]*r + lc*sv0;
  v2[t*3+1] = accV[t*3+1]*r + lc*sv1;
  v2[t*3+2] = accV[t*3+2]*r + lc*sv2;
}

// ---- edge output TP -> 5x0e ----
__global__ __launch_bounds__(256) void k_e3(
    const float* __restrict__ hE, const float* __restrict__ sh,
    const float* __restrict__ s2, const float* __restrict__ v2,
    const int* __restrict__ eidx,
    const float* __restrict__ W1, const float* __restrict__ b1,
    float* __restrict__ out) {
  __shared__ float4 EA[640];
  __shared__ float4 EB[640];
  __shared__ float bL[640];
  for (int t = threadIdx.x; t < 1280; t += 256) {
    int j = t >> 1, half = t & 1;
    const float* src = W1 + (half*4)*640 + j;
    float4 v;
    v.x = src[0]; v.y = src[640]; v.z = src[1280]; v.w = src[1920];
    if (half == 0) EA[j] = v; else EB[j] = v;
  }
  for (int t = threadIdx.x; t < 640; t += 256) bL[t] = b1[t];
  __syncthreads();
  const int g = threadIdx.x >> 5, u = threadIdx.x & 31;
  const float c = 0.08838834764831845f;   // 1/sqrt(128)
  const float is3 = 0.5773502691896258f;
  for (int e = blockIdx.x*8 + g; e < NE; e += gridDim.x*8) {
    float h[8];
#pragma unroll
    for (int k = 0; k < 8; k++) h[k] = hE[e*8+k];
    int src = eidx[e], dst = eidx[NE+e];
    float sh0 = sh[e*3+0], sh1 = sh[e*3+1], sh2 = sh[e*3+2];
    float xs = s2[src*32 + u];
    float xv0 = v2[src*96 + u*3 + 0], xv1 = v2[src*96 + u*3 + 1], xv2 = v2[src*96 + u*3 + 2];
    float xd = (xv0*sh0 + xv1*sh1 + xv2*sh2) * is3;
    float ys = s2[dst*32 + u];
    float yv0 = v2[dst*96 + u*3 + 0], yv1 = v2[dst*96 + u*3 + 1], yv2 = v2[dst*96 + u*3 + 2];
    float yd = (yv0*sh0 + yv1*sh1 + yv2*sh2) * is3;
    float part[5];
#pragma unroll
    for (int w = 0; w < 5; w++) {
      int j0 = u*5 + w;
      float w0v = bL[j0]     + dot8(h, EA[j0],     EB[j0]);
      float w1v = bL[160+j0] + dot8(h, EA[160+j0], EB[160+j0]);
      float w2v = bL[320+j0] + dot8(h, EA[320+j0], EB[320+j0]);
      float w3v = bL[480+j0] + dot8(h, EA[480+j0], EB[480+j0]);
      part[w] = xs*w0v + xd*w1v + ys*w2v + yd*w3v;
    }
#pragma unroll
    for (int off = 16; off > 0; off >>= 1) {
#pragma unroll
      for (int w = 0; w < 5; w++) part[w] += __shfl_xor(part[w], off, 32);
    }
    if (u < 5) out[e*5 + u] = c * part[u];
  }
}

// ---- node output MLP ----
__global__ void k_nodeout(const float* __restrict__ s2, const float* __restrict__ W1,
                          const float* __restrict__ W2, float* __restrict__ out) {
  int n = blockIdx.x * blockDim.x + threadIdx.x;
  if (n >= NN) return;
  float hbuf[13];
  const float i32 = 0.17677669529663687f;  // 1/sqrt(32)
#pragma unroll
  for (int j = 0; j < 13; j++) {
    float a = 0.f;
#pragma unroll 8
    for (int u = 0; u < 32; u++) a += s2[n*32 + u] * W1[u*13 + j];
    hbuf[j] = siluf(a * i32);
  }
  const float i13 = 0.2773500981126146f;   // 1/sqrt(13)
#pragma unroll
  for (int j2 = 0; j2 < 13; j2++) {
    float a = 0.f;
#pragma unroll
    for (int j = 0; j < 13; j++) a += hbuf[j] * W2[j*13 + j2];
    out[n*13 + j2] = a * i13;
  }
}

extern "C" void kernel_launch(void* const* d_in, const int* in_sizes, int n_in,
                              void* d_out, int out_size, void* d_ws, size_t ws_size,
                              hipStream_t stream) {
  (void)in_sizes; (void)n_in; (void)out_size; (void)ws_size;
  const float* coords = (const float*)d_in[0];
  const int*   atype  = (const int*)d_in[1];
  const int*   eidx   = (const int*)d_in[2];
  const float* emb    = (const float*)d_in[3];
  const float* ipW0 = (const float*)d_in[4];
  const float* ipb0 = (const float*)d_in[5];
  const float* ipW1 = (const float*)d_in[6];
  const float* ipb1 = (const float*)d_in[7];
  const float* lyW0 = (const float*)d_in[8];
  const float* lyb0 = (const float*)d_in[9];
  const float* lyW1 = (const float*)d_in[10];
  const float* lyb1 = (const float*)d_in[11];
  const float* lyWs = (const float*)d_in[12];
  const float* lyWv = (const float*)d_in[13];
  const float* etW0 = (const float*)d_in[14];
  const float* etb0 = (const float*)d_in[15];
  const float* etW1 = (const float*)d_in[16];
  const float* etb1 = (const float*)d_in[17];
  const float* noW1 = (const float*)d_in[18];
  const float* noW2 = (const float*)d_in[19];

  float* ws = (float*)d_ws;
  float* sh    = ws;                  // E*3  = 120000
  float* h_ip  = ws + 120000;         // E*8  = 320000
  float* h_ly  = ws + 440000;         // E*8
  float* h_et  = ws + 760000;         // E*8
  float* s0    = ws + 1080000;        // N*32
  float* s1    = ws + 1240000;        // N*32
  float* v1    = ws + 1400000;        // N*96
  float* s2    = ws + 1880000;        // N*32
  float* v2    = ws + 2040000;        // N*96
  float* cnt   = ws + 2520000;        // N          -- zeroed region start
  float* accS  = ws + 2525000;        // N*32
  float* accV  = ws + 2685000;        // N*96
  float* acc2S = ws + 3165000;        // N*32
  float* acc2V = ws + 3325000;        // N*96       -- ends at 3805000 floats

  float* outE = (float*)d_out;            // E*5
  float* outN = (float*)d_out + NE*5;     // N*13

  hipMemsetAsync(cnt, 0, (size_t)1285000 * sizeof(float), stream);
  k_embed<<<(NN*32 + 255)/256, 256, 0, stream>>>(atype, emb, s0);
  k_geom<<<(NE + 255)/256, 256, 0, stream>>>(coords, eidx, ipW0, ipb0, lyW0, lyb0,
                                             etW0, etb0, sh, h_ip, h_ly, h_et, cnt);
  // init conv: FCTP(32x0e, 0e+1o -> 32x0e+32x1o), c = 1/sqrt(32)
  k_sconv<<<512, 256, 0, stream>>>(h_ip, sh, s0, eidx, ipW1, ipb1, 2048, 0,
                                   0.17677669529663687f, accS, accV);
  k_n1<<<(NN*32 + 255)/256, 256, 0, stream>>>(cnt, accS, accV, s1, v1);
  // hidden conv paths {0,1} (scalar-driven), c = 1/sqrt(64)
  k_sconv<<<512, 256, 0, stream>>>(h_ly, sh, s1, eidx, lyW1, lyb1, 4096, 0,
                                   0.125f, acc2S, acc2V);
  // hidden conv paths {2,3} (vector-driven)
  k_vconv<<<512, 256, 0, stream>>>(h_ly, sh, v1, eidx, lyW1, lyb1, acc2S, acc2V);
  k_n2<<<(NN*32 + 255)/256, 256, 0, stream>>>(cnt, acc2S, acc2V, s1, v1, lyWs, lyWv, s2, v2);
  k_e3<<<512, 256, 0, stream>>>(h_et, sh, s2, v2, eidx, etW1, etb1, outE);
  k_nodeout<<<(NN + 255)/256, 256, 0, stream>>>(s2, noW1, noW2, outN);
}